// Round 1
// baseline (2258.966 us; speedup 1.0000x reference)
//
#include <hip/hip_runtime.h>
#include <math.h>

#define B_ 16
#define C_IN 64
#define C_OUT 64
#define H_ 256
#define W_ 256
#define NK 4
#define NGROUPS 8
#define CH_PER_G (C_OUT / NGROUPS)   // 8

#define WMOD_FLOATS (B_ * C_IN * 9 * C_OUT)   // 589824, layout [b][i*9+k][o]
#define STATS_FLOATS (B_ * NGROUPS * 2)       // 256

// ---------------------------------------------------------------------------
// Kernel 1: per-batch modulated+demodulated weights.
// grid = (b*o) blocks of 64 threads (one wave). lane = input channel i.
// Output layout: wmod[b][i*9+k][o]  (o contiguous -> uniform float4 loads in conv)
// ---------------------------------------------------------------------------
__global__ __launch_bounds__(64)
void k_weights(const float* __restrict__ mod, const float* __restrict__ kmod,
               const float* __restrict__ cw, float* __restrict__ wmod) {
    int bo = blockIdx.x;
    int b = bo >> 6, o = bo & 63;
    int lane = threadIdx.x;   // = input channel i

    // softmax over 4 kernel logits (redundant per lane, trivial)
    float a0 = kmod[b * NK + 0], a1 = kmod[b * NK + 1];
    float a2 = kmod[b * NK + 2], a3 = kmod[b * NK + 3];
    float m = fmaxf(fmaxf(a0, a1), fmaxf(a2, a3));
    float e0 = __expf(a0 - m), e1 = __expf(a1 - m);
    float e2 = __expf(a2 - m), e3 = __expf(a3 - m);
    float inv = 1.0f / (e0 + e1 + e2 + e3);
    e0 *= inv; e1 *= inv; e2 *= inv; e3 *= inv;

    float modv = mod[b * C_IN + lane] + 1.0f;

    float wv[9];
    float ss = 0.0f;
#pragma unroll
    for (int j = 0; j < 9; ++j) {
        int idx = o * 576 + lane * 9 + j;       // [o][i][k] within one kernel
        float w = cw[0 * C_OUT * 576 + idx] * e0
                + cw[1 * C_OUT * 576 + idx] * e1
                + cw[2 * C_OUT * 576 + idx] * e2
                + cw[3 * C_OUT * 576 + idx] * e3;
        w *= modv;
        wv[j] = w;
        ss += w * w;
    }
    // wave-wide sum of squares (64 lanes)
#pragma unroll
    for (int off = 32; off > 0; off >>= 1)
        ss += __shfl_xor(ss, off, 64);
    float invn = rsqrtf(fmaxf(ss, 1e-8f));
#pragma unroll
    for (int j = 0; j < 9; ++j)
        wmod[b * (C_IN * 9 * C_OUT) + (lane * 9 + j) * C_OUT + o] = wv[j] * invn;
}

// ---------------------------------------------------------------------------
// Kernel 2: direct 3x3 conv, fp32.
// grid = (64 tiles of 32x32, 4 o-groups of 16, 16 batches), 256 threads.
// Thread owns a 1x4 pixel strip x 16 output channels -> 64 accumulators.
// x staged in LDS (pad to 40 -> 2-way max bank conflict = free).
// Weights: wave-uniform global loads -> scalar s_load path.
// Epilogue: write raw conv to y, wave-reduced atomic sum/sumsq per (b,group).
// ---------------------------------------------------------------------------
#define ICC 8
__global__ __launch_bounds__(256)
void k_conv(const float* __restrict__ x, const float* __restrict__ wmod,
            float* __restrict__ y, float* __restrict__ stats) {
    __shared__ float xs[ICC][34][40];

    const int tile = blockIdx.x;           // 0..63
    const int og   = blockIdx.y;           // 0..3
    const int b    = blockIdx.z;           // 0..15
    const int ty0  = (tile >> 3) * 32;
    const int tx0  = (tile & 7) * 32;
    const int o0   = og * 16;

    const int tid = threadIdx.x;
    const int ty  = tid >> 3;              // 0..31
    const int tx4 = (tid & 7) * 4;         // 0,4,...,28

    float acc[16][4];
#pragma unroll
    for (int oo = 0; oo < 16; ++oo)
#pragma unroll
        for (int pp = 0; pp < 4; ++pp) acc[oo][pp] = 0.0f;

    const float* wb = wmod + b * (C_IN * 9 * C_OUT) + o0;

    for (int ic0 = 0; ic0 < C_IN; ic0 += ICC) {
        __syncthreads();
        // stage x tile (34x34 halo region per channel)
        for (int idx = tid; idx < ICC * 34 * 34; idx += 256) {
            int i   = idx / (34 * 34);
            int rem = idx - i * (34 * 34);
            int r   = rem / 34;
            int c   = rem - r * 34;
            int gr = ty0 - 1 + r;
            int gc = tx0 - 1 + c;
            float v = 0.0f;
            if ((unsigned)gr < H_ && (unsigned)gc < W_)
                v = x[((b * C_IN + ic0 + i) * H_ + gr) * W_ + gc];
            xs[i][r][c] = v;
        }
        __syncthreads();

#pragma unroll 2
        for (int i = 0; i < ICC; ++i) {
#pragma unroll
            for (int dy = 0; dy < 3; ++dy) {
                const float4 xa = *(const float4*)&xs[i][ty + dy][tx4];
                const float2 xb = *(const float2*)&xs[i][ty + dy][tx4 + 4];
                float xw[6] = {xa.x, xa.y, xa.z, xa.w, xb.x, xb.y};
#pragma unroll
                for (int dx = 0; dx < 3; ++dx) {
                    const float* wp = wb + ((ic0 + i) * 9 + dy * 3 + dx) * C_OUT;
                    const float4 w0 = *(const float4*)(wp + 0);
                    const float4 w1 = *(const float4*)(wp + 4);
                    const float4 w2 = *(const float4*)(wp + 8);
                    const float4 w3 = *(const float4*)(wp + 12);
                    float wv[16] = {w0.x, w0.y, w0.z, w0.w,
                                    w1.x, w1.y, w1.z, w1.w,
                                    w2.x, w2.y, w2.z, w2.w,
                                    w3.x, w3.y, w3.z, w3.w};
#pragma unroll
                    for (int oo = 0; oo < 16; ++oo)
#pragma unroll
                        for (int pp = 0; pp < 4; ++pp)
                            acc[oo][pp] = fmaf(xw[pp + dx], wv[oo], acc[oo][pp]);
                }
            }
        }
    }

    // write raw conv output (float4 per oo)
#pragma unroll
    for (int oo = 0; oo < 16; ++oo) {
        float4 v = make_float4(acc[oo][0], acc[oo][1], acc[oo][2], acc[oo][3]);
        *(float4*)&y[((b * C_OUT + o0 + oo) * H_ + (ty0 + ty)) * W_ + tx0 + tx4] = v;
    }

    // GroupNorm partial sums: oo 0..7 -> group o0/8, oo 8..15 -> group o0/8+1
    float s0 = 0.f, q0 = 0.f, s1 = 0.f, q1 = 0.f;
#pragma unroll
    for (int oo = 0; oo < 8; ++oo)
#pragma unroll
        for (int pp = 0; pp < 4; ++pp) {
            float v = acc[oo][pp];
            s0 += v; q0 += v * v;
        }
#pragma unroll
    for (int oo = 8; oo < 16; ++oo)
#pragma unroll
        for (int pp = 0; pp < 4; ++pp) {
            float v = acc[oo][pp];
            s1 += v; q1 += v * v;
        }
#pragma unroll
    for (int off = 32; off > 0; off >>= 1) {
        s0 += __shfl_xor(s0, off, 64);
        q0 += __shfl_xor(q0, off, 64);
        s1 += __shfl_xor(s1, off, 64);
        q1 += __shfl_xor(q1, off, 64);
    }
    if ((tid & 63) == 0) {
        int g0 = o0 >> 3;   // 2 groups per o-block
        atomicAdd(&stats[(b * NGROUPS + g0) * 2 + 0], s0);
        atomicAdd(&stats[(b * NGROUPS + g0) * 2 + 1], q0);
        atomicAdd(&stats[(b * NGROUPS + g0 + 1) * 2 + 0], s1);
        atomicAdd(&stats[(b * NGROUPS + g0 + 1) * 2 + 1], q1);
    }
}

// ---------------------------------------------------------------------------
// Kernel 3: GroupNorm apply + SiLU, in place on y (= d_out), float4 per thread.
// 64 blocks per channel -> stats index is block-uniform (scalar loads).
// ---------------------------------------------------------------------------
__global__ __launch_bounds__(256)
void k_norm(float4* __restrict__ y, const float* __restrict__ stats,
            const float* __restrict__ gamma, const float* __restrict__ beta) {
    const int cg = blockIdx.x >> 6;        // global channel 0..1023 (b*64+ch)
    const int b  = cg >> 6;
    const int ch = cg & 63;
    const int g  = ch >> 3;

    const float sum = stats[(b * NGROUPS + g) * 2 + 0];
    const float ssq = stats[(b * NGROUPS + g) * 2 + 1];
    const float invN = 1.0f / (float)(CH_PER_G * H_ * W_);
    const float mean = sum * invN;
    const float var  = fmaxf(ssq * invN - mean * mean, 0.0f);
    const float rstd = rsqrtf(var + 1e-5f);
    const float ga = gamma[ch] * rstd;
    const float be = beta[ch] - mean * ga;

    const int idx = blockIdx.x * 256 + threadIdx.x;   // float4 index
    float4 v = y[idx];
    float t;
    t = v.x * ga + be; v.x = t / (1.0f + __expf(-t));
    t = v.y * ga + be; v.y = t / (1.0f + __expf(-t));
    t = v.z * ga + be; v.z = t / (1.0f + __expf(-t));
    t = v.w * ga + be; v.w = t / (1.0f + __expf(-t));
    y[idx] = v;
}

// ---------------------------------------------------------------------------
extern "C" void kernel_launch(void* const* d_in, const int* in_sizes, int n_in,
                              void* d_out, int out_size, void* d_ws, size_t ws_size,
                              hipStream_t stream) {
    const float* x     = (const float*)d_in[0];
    const float* mod   = (const float*)d_in[1];
    const float* kmod  = (const float*)d_in[2];
    const float* cw    = (const float*)d_in[3];
    const float* gamma = (const float*)d_in[4];
    const float* beta  = (const float*)d_in[5];
    float* out = (float*)d_out;

    float* wmod  = (float*)d_ws;
    float* stats = wmod + WMOD_FLOATS;

    k_weights<<<dim3(B_ * C_OUT), dim3(64), 0, stream>>>(mod, kmod, cw, wmod);
    hipMemsetAsync(stats, 0, STATS_FLOATS * sizeof(float), stream);

    dim3 cgrid(64, 4, B_);
    k_conv<<<cgrid, dim3(256), 0, stream>>>(x, wmod, out, stats);

    k_norm<<<dim3(B_ * C_OUT * 64), dim3(256), 0, stream>>>(
        (float4*)out, stats, gamma, beta);
}

// Round 2
// 891.404 us; speedup vs baseline: 2.5342x; 2.5342x over previous
//
#include <hip/hip_runtime.h>
#include <hip/hip_bf16.h>
#include <math.h>

#define B_ 16
#define C_IN 64
#define C_OUT 64
#define H_ 256
#define W_ 256
#define NK 4
#define NGROUPS 8
#define CH_PER_G (C_OUT / NGROUPS)

#define WM16_SHORTS (B_ * C_OUT * 9 * C_IN)       // 589824 bf16, [b][o][tap][i]
#define STATS_FLOATS (B_ * NGROUPS * 2)           // 256

typedef __attribute__((ext_vector_type(8))) short bf16x8;
typedef __attribute__((ext_vector_type(4))) float f32x4;

static __device__ __forceinline__ unsigned bf16bits(float v) {
    return (unsigned)__builtin_bit_cast(unsigned short, __float2bfloat16(v));
}

// ---------------------------------------------------------------------------
// Kernel 1: blend(softmax) + modulate + demodulate, output bf16 [b][o][tap][i]
// grid = b*o waves; lane = input channel i.
// ---------------------------------------------------------------------------
__global__ __launch_bounds__(64)
void k_weights(const float* __restrict__ mod, const float* __restrict__ kmod,
               const float* __restrict__ cw, unsigned short* __restrict__ wm16) {
    int bo = blockIdx.x;
    int b = bo >> 6, o = bo & 63;
    int lane = threadIdx.x;   // input channel i

    float a0 = kmod[b * NK + 0], a1 = kmod[b * NK + 1];
    float a2 = kmod[b * NK + 2], a3 = kmod[b * NK + 3];
    float m = fmaxf(fmaxf(a0, a1), fmaxf(a2, a3));
    float e0 = __expf(a0 - m), e1 = __expf(a1 - m);
    float e2 = __expf(a2 - m), e3 = __expf(a3 - m);
    float inv = 1.0f / (e0 + e1 + e2 + e3);
    e0 *= inv; e1 *= inv; e2 *= inv; e3 *= inv;

    float modv = mod[b * C_IN + lane] + 1.0f;

    float wv[9];
    float ss = 0.0f;
#pragma unroll
    for (int j = 0; j < 9; ++j) {
        int idx = o * 576 + lane * 9 + j;
        float w = cw[0 * C_OUT * 576 + idx] * e0
                + cw[1 * C_OUT * 576 + idx] * e1
                + cw[2 * C_OUT * 576 + idx] * e2
                + cw[3 * C_OUT * 576 + idx] * e3;
        w *= modv;
        wv[j] = w;
        ss += w * w;
    }
#pragma unroll
    for (int off = 32; off > 0; off >>= 1)
        ss += __shfl_xor(ss, off, 64);
    float invn = rsqrtf(fmaxf(ss, 1e-8f));
#pragma unroll
    for (int j = 0; j < 9; ++j)
        wm16[((b * 64 + o) * 9 + j) * 64 + lane] =
            (unsigned short)bf16bits(wv[j] * invn);
}

// ---------------------------------------------------------------------------
// Kernel 2: implicit-GEMM conv via MFMA bf16.
// Block: 64 o x 256 px (spatial 32 wide x 8 tall). 4 waves, each 4x4 tiles of
// 16x16x32 MFMA. X staged once in LDS: 340 pixel slots (10x34 halo) x 64 ch
// bf16, 128 B per pixel, 16B-chunk XOR swizzle (chunk ^ (slot&7)) so both
// staging b128 writes and B-frag b128 reads are bank-even.
// A-frags (weights) load from global (L2-resident, 73 KB/batch).
// Epilogue: fp32 y to d_out + fused GroupNorm partial sums (LDS -> global atomics).
// ---------------------------------------------------------------------------
#define NSLOT 340           // 10 * 34
#define LDSBYTES (NSLOT * 128)

__global__ __launch_bounds__(256, 3)
void k_conv(const float* __restrict__ x, const unsigned short* __restrict__ wm16,
            float* __restrict__ y, float* __restrict__ stats) {
    __shared__ __align__(16) char smem[LDSBYTES];
    __shared__ float lst[16];

    const int tile = blockIdx.x;          // 0..255
    const int b    = blockIdx.y;          // 0..15
    const int R0   = (tile >> 3) * 8;
    const int C0   = (tile & 7) * 32;
    const int tid  = threadIdx.x;
    const int w    = tid >> 6;            // wave 0..3
    const int lane = tid & 63;
    const int l15  = lane & 15;
    const int q    = lane >> 4;           // 0..3

    if (tid < 16) lst[tid] = 0.0f;

    // ---- stage X (fp32 -> bf16, transpose to [pixel][ch], swizzled) ----
    for (int t = tid; t < NSLOT * 8; t += 256) {
        int chunk = t / NSLOT;            // 8-channel chunk 0..7
        int slot  = t - chunk * NSLOT;    // pixel slot 0..339
        int r = slot / 34;
        int c = slot - r * 34;
        int gr = R0 - 1 + r;
        int gc = C0 - 1 + c;
        bool ok = ((unsigned)gr < (unsigned)H_) && ((unsigned)gc < (unsigned)W_);
        const float* xp = x + (((b * 64 + chunk * 8) * 256 + gr) * 256 + gc);
        unsigned u[4];
#pragma unroll
        for (int jj = 0; jj < 4; ++jj) {
            float v0 = ok ? xp[(2 * jj) * 65536] : 0.0f;
            float v1 = ok ? xp[(2 * jj + 1) * 65536] : 0.0f;
            u[jj] = (bf16bits(v1) << 16) | bf16bits(v0);
        }
        *(int4*)(smem + slot * 128 + ((chunk ^ (slot & 7)) << 4)) =
            make_int4(u[0], u[1], u[2], u[3]);
    }
    __syncthreads();

    // ---- MFMA main loop: 9 taps x 2 k-chunks of 32 channels ----
    f32x4 acc[4][4];
#pragma unroll
    for (int mt = 0; mt < 4; ++mt)
#pragma unroll
        for (int nt = 0; nt < 4; ++nt)
            acc[mt][nt] = (f32x4){0.f, 0.f, 0.f, 0.f};

    const unsigned short* wb = wm16 + b * (64 * 9 * 64);

    for (int tap = 0; tap < 9; ++tap) {
        const int ky = tap / 3;
        const int kx = tap - ky * 3;

        bf16x8 af[4][2];
#pragma unroll
        for (int mt = 0; mt < 4; ++mt)
#pragma unroll
            for (int kc = 0; kc < 2; ++kc)
                af[mt][kc] = *(const bf16x8*)(wb +
                    ((mt * 16 + l15) * 9 + tap) * 64 + kc * 32 + q * 8);

#pragma unroll
        for (int kc = 0; kc < 2; ++kc) {
            bf16x8 bfr[4];
#pragma unroll
            for (int nt = 0; nt < 4; ++nt) {
                int ro = 2 * w + (nt >> 1);          // output row in tile
                int c0 = (nt & 1) * 16;              // col half
                int slot = (ro + ky) * 34 + c0 + kx + l15;
                int chunk = kc * 4 + q;
                bfr[nt] = *(const bf16x8*)(smem + slot * 128 +
                                           ((chunk ^ (slot & 7)) << 4));
            }
#pragma unroll
            for (int mt = 0; mt < 4; ++mt)
#pragma unroll
                for (int nt = 0; nt < 4; ++nt)
                    acc[mt][nt] = __builtin_amdgcn_mfma_f32_16x16x32_bf16(
                        af[mt][kc], bfr[nt], acc[mt][nt], 0, 0, 0);
        }
    }

    // ---- epilogue: store y (fp32), fused GroupNorm partial sums ----
    // D layout: o = mt*16 + q*4 + reg, px_col = l15
    float sg[4] = {0.f, 0.f, 0.f, 0.f};
    float qg[4] = {0.f, 0.f, 0.f, 0.f};
#pragma unroll
    for (int mt = 0; mt < 4; ++mt) {
#pragma unroll
        for (int nt = 0; nt < 4; ++nt) {
            int ro = 2 * w + (nt >> 1);
            int c0 = (nt & 1) * 16;
            float* yp = y + ((b * 64 + mt * 16 + q * 4) * 65536 +
                             (R0 + ro) * 256 + C0 + c0 + l15);
#pragma unroll
            for (int r = 0; r < 4; ++r) {
                float v = acc[mt][nt][r];
                yp[r * 65536] = v;
                sg[mt] += v;
                qg[mt] += v * v;
            }
        }
    }
    const int gsel = q >> 1;   // lane's o in group 2*mt + gsel
#pragma unroll
    for (int mt = 0; mt < 4; ++mt) {
        atomicAdd(&lst[(2 * mt + gsel) * 2 + 0], sg[mt]);
        atomicAdd(&lst[(2 * mt + gsel) * 2 + 1], qg[mt]);
    }
    __syncthreads();
    if (tid < 16) atomicAdd(&stats[b * 16 + tid], lst[tid]);
}

// ---------------------------------------------------------------------------
// Kernel 3: GroupNorm apply + SiLU in place on d_out.
// ---------------------------------------------------------------------------
__global__ __launch_bounds__(256)
void k_norm(float4* __restrict__ y, const float* __restrict__ stats,
            const float* __restrict__ gamma, const float* __restrict__ beta) {
    const int cg = blockIdx.x >> 6;       // b*64 + ch
    const int b  = cg >> 6;
    const int ch = cg & 63;
    const int g  = ch >> 3;

    const float sum = stats[(b * NGROUPS + g) * 2 + 0];
    const float ssq = stats[(b * NGROUPS + g) * 2 + 1];
    const float invN = 1.0f / (float)(CH_PER_G * H_ * W_);
    const float mean = sum * invN;
    const float var  = fmaxf(ssq * invN - mean * mean, 0.0f);
    const float rstd = rsqrtf(var + 1e-5f);
    const float ga = gamma[ch] * rstd;
    const float be = beta[ch] - mean * ga;

    const int idx = blockIdx.x * 256 + threadIdx.x;
    float4 v = y[idx];
    float t;
    t = v.x * ga + be; v.x = t / (1.0f + __expf(-t));
    t = v.y * ga + be; v.y = t / (1.0f + __expf(-t));
    t = v.z * ga + be; v.z = t / (1.0f + __expf(-t));
    t = v.w * ga + be; v.w = t / (1.0f + __expf(-t));
    y[idx] = v;
}

// ---------------------------------------------------------------------------
extern "C" void kernel_launch(void* const* d_in, const int* in_sizes, int n_in,
                              void* d_out, int out_size, void* d_ws, size_t ws_size,
                              hipStream_t stream) {
    const float* x     = (const float*)d_in[0];
    const float* mod   = (const float*)d_in[1];
    const float* kmod  = (const float*)d_in[2];
    const float* cw    = (const float*)d_in[3];
    const float* gamma = (const float*)d_in[4];
    const float* beta  = (const float*)d_in[5];
    float* out = (float*)d_out;

    unsigned short* wm16 = (unsigned short*)d_ws;
    float* stats = (float*)((char*)d_ws + WM16_SHORTS * sizeof(unsigned short));

    k_weights<<<dim3(B_ * C_OUT), dim3(64), 0, stream>>>(mod, kmod, cw, wm16);
    hipMemsetAsync(stats, 0, STATS_FLOATS * sizeof(float), stream);

    k_conv<<<dim3(256, B_), dim3(256), 0, stream>>>(x, wm16, out, stats);

    k_norm<<<dim3(B_ * C_OUT * 64), dim3(256), 0, stream>>>(
        (float4*)out, stats, gamma, beta);
}